// Round 5
// baseline (709.013 us; speedup 1.0000x reference)
//
#include <hip/hip_runtime.h>
#include <cstdint>

typedef short short8 __attribute__((ext_vector_type(8)));
typedef float f32x16 __attribute__((ext_vector_type(16)));

// Problem constants
#define NB 4
#define NN 4096
#define ND 576
#define BIGI 0x7FFFFFFF
#define NSLICE 4

// ws layout: A_hi (bf16) [b][tile128][kc18][512 chunks of 16B] = 9437184 shorts,
// then A_lo same size; then (float units):
#define INVN_OFF 9437184
#define CANDV_OFF 9439488
#define CANDI_OFF 9636096
// total = 9832704 floats = 39.33 MB
// Chunk swizzle (baked into layout): chunk g = r*4 + c', source chunk
// c = c' ^ ((r>>1)&3), i.e. source k-span = c*8..c*8+7 of row r.

#define MFMA __builtin_amdgcn_mfma_f32_32x32x16_bf16

__device__ __forceinline__ unsigned short f2bf(float f) {
    unsigned u = __float_as_uint(f);
    u += 0x7FFFu + ((u >> 16) & 1u);   // round-to-nearest-even
    return (unsigned short)(u >> 16);
}

__device__ __forceinline__ void gload_lds16(const void* g, void* l) {
    __builtin_amdgcn_global_load_lds(
        (const __attribute__((address_space(1))) void*)g,
        (__attribute__((address_space(3))) void*)l, 16, 0, 0);
}

// Exact jax top_k comparator: bigger value wins; tie -> smaller index wins.
__device__ __forceinline__ void insert_cmp(float v, int m,
    float& v0, int& i0, float& v1, int& i1, float& v2, int& i2) {
    bool beat2 = (v > v2) || (v == v2 && m < i2);
    if (beat2) {
        bool beat1 = (v > v1) || (v == v1 && m < i1);
        if (beat1) {
            v2 = v1; i2 = i1;
            bool beat0 = (v > v0) || (v == v0 && m < i0);
            if (beat0) { v1 = v0; i1 = i0; v0 = v; i0 = m; }
            else       { v1 = v;  i1 = m; }
        } else { v2 = v; i2 = m; }
    }
}

// Kernel 1: per-(b,c) windowed sums of x^2 -> inv norms for the 9 kernel offsets.
__global__ __launch_bounds__(64) void norm_kernel(const float* __restrict__ x,
                                                  float* __restrict__ ws) {
    const int bc = blockIdx.x;          // b*64 + c
    const int lane = threadIdx.x;       // = column w
    const float* xp = x + ((size_t)bc << 12);
    float colsum = 0.f, v0 = 0.f, v63 = 0.f;
    for (int h = 0; h < 64; ++h) {
        const float val = xp[(h << 6) + lane];
        const float sq = val * val;
        colsum += sq;
        if (h == 0)  v0 = sq;
        if (h == 63) v63 = sq;
    }
    float total = colsum, row0 = v0, row63 = v63;
    #pragma unroll
    for (int o = 32; o > 0; o >>= 1) {
        total += __shfl_xor(total, o);
        row0  += __shfl_xor(row0, o);
        row63 += __shfl_xor(row63, o);
    }
    const float col0  = __shfl(colsum, 0);
    const float col63 = __shfl(colsum, 63);
    const float c00 = __shfl(v0, 0),  c0e = __shfl(v0, 63);
    const float ce0 = __shfl(v63, 0), cee = __shfl(v63, 63);
    if (lane < 9) {
        const int dh = lane / 3 - 1, dw = lane % 3 - 1;
        float S = total;
        if (dh == 1)  S -= row0;
        if (dh == -1) S -= row63;
        if (dw == 1)  S -= col0;
        if (dw == -1) S -= col63;
        if (dh == 1  && dw == 1)  S += c00;
        if (dh == 1  && dw == -1) S += c0e;
        if (dh == -1 && dw == 1)  S += ce0;
        if (dh == -1 && dw == -1) S += cee;
        float nrm = fmaxf(sqrtf(S), 1e-12f);
        ws[INVN_OFF + bc * 9 + lane] = 1.0f / nrm;
    }
}

// Kernel 2: split-bf16 materialization with baked chunk swizzle.
// blockIdx = (b*32+nt)*18+kc. Region = 512 chunks of 16B (8 bf16).
__global__ __launch_bounds__(256) void mat_kernel(const float* __restrict__ x,
                                                  float* __restrict__ ws) {
    const int bi = blockIdx.x;             // 2304 blocks
    const int b = bi / 576;
    const int rem = bi - b * 576;
    const int nt = rem / 18;
    const int kc = rem - nt * 18;
    unsigned short* AH = (unsigned short*)ws;
    unsigned short* AL = AH + 9437184;
    const float* invn = ws + INVN_OFF + b * 576;
    const int tid = threadIdx.x;
    #pragma unroll
    for (int hf2 = 0; hf2 < 2; ++hf2) {
        const int g = tid + hf2 * 256;     // output chunk 0..511
        const int row = g >> 2, cp = g & 3;
        const int c = cp ^ ((row >> 1) & 3);    // source chunk (swizzle)
        const int k0 = c * 8;
        const int n = nt * 128 + row;
        const int h = n >> 6, wc = n & 63;
        union { unsigned short us[8]; float4 f4; } uh, ul;
        #pragma unroll
        for (int j = 0; j < 8; ++j) {
            const int d = kc * 32 + k0 + j;
            const int ch = d / 9;
            const int p = d - ch * 9;
            const int r = h + p / 3 - 1, s2 = wc + p % 3 - 1;
            float val = 0.f;
            if ((unsigned)r < 64u && (unsigned)s2 < 64u)
                val = x[((size_t)(b * 64 + ch) << 12) + (r << 6) + s2];
            val *= invn[d];
            const unsigned short hb = f2bf(val);
            const float hfv = __uint_as_float(((unsigned)hb) << 16);
            const unsigned short lb = f2bf(val - hfv);
            uh.us[j] = hb; ul.us[j] = lb;
        }
        ((float4*)AH)[(size_t)bi * 512 + g] = uh.f4;
        ((float4*)AL)[(size_t)bi * 512 + g] = ul.f4;
    }
}

__device__ __forceinline__ short8 ldfrag(const short* p) {
    union { short8 s8; float4 f4; } u;
    u.f4 = *(const float4*)p;
    return u.s8;
}

// Kernel 3: R = A^T A via split-bf16 MFMA (hh + hl + lh), fused top-3.
// OCCUPANCY-FIRST variant: the invariant across R0-R4 was 8 waves/CU
// (2/SIMD, register-capped: V ~100 + acc AGPRs). Shrink per-wave state so
// 3 waves/SIMD fit: wave tile 64n x 64m -> acc[2][2] = 64 AGPR, V target
// <= ~100, enforced by __launch_bounds__(256,3).
// Grid 1024 = b(4) x nt(64: 64-row n-panels) x s(4) -> 4 blocks/CU offered.
// Block: 256 thr = 4 waves along m; per mt covers 64n x 256m, mt=0..3 over
// the 1024-m slice.  An (shared): LDS, 2 x 8KB double buffer, issue-early,
// one __syncthreads per kc.  Am (wave-private): direct global->VGPR.
// C/D: m_part = (reg&3)+8*(reg>>2)+4*(lane>>5), n_part = lane&31  [HW-verified]
__global__ void __launch_bounds__(256, 3) gram_kernel(float* ws) {
    __shared__ short sm[8192];   // 16 KB: buf0 {AnH[2048] AnL[2048]}, buf1 same
    const int bx0 = blockIdx.x;
    const int bx = ((bx0 & 7) << 7) | (bx0 >> 3);   // XCD swizzle (1024 = 8*128, bijective)
    const int b  = bx >> 8;
    const int nt = (bx >> 2) & 63;     // 64-row n-panel
    const int s  = bx & 3;
    const int tid = threadIdx.x;
    const int w = tid >> 6, lane = tid & 63;
    const int l31 = lane & 31, kh2 = lane >> 5;

    const unsigned short* AH = (const unsigned short*)ws;
    const unsigned short* AL = AH + 9437184;

    const int nReg = (b * 32 + (nt >> 1)) * 18;     // 128-row region; + kc
    const int nHalf = (nt & 1) * 2048;              // 64-row half (shorts)

    // An frag LDS offsets within one buffer (shorts): H at 0, L at +2048.
    // frag(row r, src chunk c) at r*32 + ((c ^ ((r>>1)&3))<<3), c = kh2 + 2h
    int boff[2][2];
    #pragma unroll
    for (int ni = 0; ni < 2; ++ni)
        #pragma unroll
        for (int h = 0; h < 2; ++h) {
            const int r = ni * 32 + l31;            // 0..63
            const int c = kh2 + 2 * h;
            boff[ni][h] = r * 32 + ((c ^ ((r >> 1) & 3)) << 3);
        }

    float t0v[2], t1v[2], t2v[2];
    int   t0i[2], t1i[2], t2i[2];
    #pragma unroll
    for (int i = 0; i < 2; ++i) {
        t0v[i] = t1v[i] = t2v[i] = -INFINITY;
        t0i[i] = t1i[i] = t2i[i] = BIGI;
    }

    // prologue: stage An[kc=0] into buffer 0 (8 KB: 2 instr/thread)
    {
        const unsigned short* gH = AH + (size_t)nReg * 4096 + nHalf + tid * 8;
        const unsigned short* gL = AL + (size_t)nReg * 4096 + nHalf + tid * 8;
        gload_lds16(gH, sm + tid * 8);
        gload_lds16(gL, sm + 2048 + tid * 8);
    }
    __syncthreads();

    for (int mt = 0; mt < 4; ++mt) {
        // Am meta for this mt: wave w owns m-cols mt*256 + w*64 .. +63
        int regIdx[2], amoff[2][2];
        #pragma unroll
        for (int mi = 0; mi < 2; ++mi) {
            const int mrow = s * 1024 + mt * 256 + w * 64 + mi * 32 + l31;  // 0..4095
            regIdx[mi] = (b * 32 + (mrow >> 7)) * 18;
            const int rl = mrow & 127;
            #pragma unroll
            for (int h = 0; h < 2; ++h) {
                const int c = kh2 + 2 * h;
                amoff[mi][h] = rl * 32 + ((c ^ ((rl >> 1) & 3)) << 3);
            }
        }

        f32x16 acc[2][2];   // [mi][ni]
        #pragma unroll
        for (int mi = 0; mi < 2; ++mi)
            #pragma unroll
            for (int ni = 0; ni < 2; ++ni)
                #pragma unroll
                for (int e = 0; e < 16; ++e) acc[mi][ni][e] = 0.f;

        for (int kc = 0; kc < 18; ++kc) {
            const int cur = kc & 1;     // 18 even -> parity consistent across mt
            // issue next An stage first (overlaps with this kc's compute)
            if (!(mt == 3 && kc == 17)) {
                const int nk = (kc + 1 == 18) ? 0 : kc + 1;
                const unsigned short* gH = AH + (size_t)(nReg + nk) * 4096 + nHalf + tid * 8;
                const unsigned short* gL = AL + (size_t)(nReg + nk) * 4096 + nHalf + tid * 8;
                short* dstb = sm + ((cur ^ 1) << 12);
                gload_lds16(gH, dstb + tid * 8);
                gload_lds16(gL, dstb + 2048 + tid * 8);
            }
            // Am fragments: direct global->VGPR (wave-private)
            short8 amh[2][2], aml[2][2];   // [mi][h]
            #pragma unroll
            for (int mi = 0; mi < 2; ++mi) {
                const short* rH = (const short*)(AH + (size_t)(regIdx[mi] + kc) * 4096);
                const short* rL = (const short*)(AL + (size_t)(regIdx[mi] + kc) * 4096);
                #pragma unroll
                for (int h = 0; h < 2; ++h) {
                    amh[mi][h] = ldfrag(rH + amoff[mi][h]);
                    aml[mi][h] = ldfrag(rL + amoff[mi][h]);
                }
            }
            // An from LDS buffer cur + MFMA
            const short* sb = sm + (cur << 12);
            #pragma unroll
            for (int h = 0; h < 2; ++h) {
                #pragma unroll
                for (int ni = 0; ni < 2; ++ni) {
                    const short8 bh = ldfrag(sb + boff[ni][h]);
                    const short8 bl = ldfrag(sb + boff[ni][h] + 2048);
                    #pragma unroll
                    for (int mi = 0; mi < 2; ++mi) {
                        acc[mi][ni] = MFMA(amh[mi][h], bh, acc[mi][ni], 0, 0, 0);
                        acc[mi][ni] = MFMA(amh[mi][h], bl, acc[mi][ni], 0, 0, 0);
                        acc[mi][ni] = MFMA(aml[mi][h], bh, acc[mi][ni], 0, 0, 0);
                    }
                }
            }
            // one barrier per kc: prior reads of buf cur drained before re-stage;
            // staged buf cur^1 complete (vmcnt drained by barrier) for kc+1.
            __syncthreads();
        }
        // fold acc into per-lane top-3 (per ni; n = ni*32 + l31)
        const int mbase = s * 1024 + mt * 256 + w * 64 + (kh2 << 2);
        #pragma unroll
        for (int ni = 0; ni < 2; ++ni)
            #pragma unroll
            for (int mi = 0; mi < 2; ++mi)
                #pragma unroll
                for (int v = 0; v < 16; ++v) {
                    const int m = mbase + mi * 32 + (v & 3) + 8 * (v >> 2);
                    insert_cmp(acc[mi][ni][v], m,
                               t0v[ni], t0i[ni], t1v[ni], t1i[ni], t2v[ni], t2i[ni]);
                }
    }

    // merge the two kh2 halves (same n, disjoint m) via shfl
    #pragma unroll
    for (int ni = 0; ni < 2; ++ni) {
        const float pv0 = __shfl_xor(t0v[ni], 32);
        const float pv1 = __shfl_xor(t1v[ni], 32);
        const float pv2 = __shfl_xor(t2v[ni], 32);
        const int pi0 = __shfl_xor(t0i[ni], 32);
        const int pi1 = __shfl_xor(t1i[ni], 32);
        const int pi2 = __shfl_xor(t2i[ni], 32);
        insert_cmp(pv0, pi0, t0v[ni], t0i[ni], t1v[ni], t1i[ni], t2v[ni], t2i[ni]);
        insert_cmp(pv1, pi1, t0v[ni], t0i[ni], t1v[ni], t1i[ni], t2v[ni], t2i[ni]);
        insert_cmp(pv2, pi2, t0v[ni], t0i[ni], t1v[ni], t1i[ni], t2v[ni], t2i[ni]);
    }
    // cross-wave merge through LDS (4 waves share the 64 n-rows, disjoint m)
    __syncthreads();
    float* cv = (float*)sm;              // [w4][ni2][l32][3] floats (3 KB)
    int*   ci = (int*)sm + 768;          // same shape (3 KB)
    if (kh2 == 0) {
        #pragma unroll
        for (int ni = 0; ni < 2; ++ni) {
            const int base = ((w * 2 + ni) * 32 + l31) * 3;
            cv[base] = t0v[ni]; cv[base + 1] = t1v[ni]; cv[base + 2] = t2v[ni];
            ci[base] = t0i[ni]; ci[base + 1] = t1i[ni]; ci[base + 2] = t2i[ni];
        }
    }
    __syncthreads();
    if (tid < 64) {
        const int ni = tid >> 5, l = tid & 31;
        float v0 = -INFINITY, v1 = -INFINITY, v2 = -INFINITY;
        int i0 = BIGI, i1 = BIGI, i2 = BIGI;
        #pragma unroll
        for (int w2 = 0; w2 < 4; ++w2) {
            const int base = ((w2 * 2 + ni) * 32 + l) * 3;
            #pragma unroll
            for (int j = 0; j < 3; ++j)
                insert_cmp(cv[base + j], ci[base + j], v0, i0, v1, i1, v2, i2);
        }
        const int n_global = nt * 64 + tid;
        const size_t o = ((size_t)(b * NSLICE + s) * NN + n_global) * 3;
        ws[CANDV_OFF + o] = v0; ws[CANDV_OFF + o + 1] = v1; ws[CANDV_OFF + o + 2] = v2;
        int* wi = (int*)ws;
        wi[CANDI_OFF + o] = i0; wi[CANDI_OFF + o + 1] = i1; wi[CANDI_OFF + o + 2] = i2;
    }
}

// Kernel 4: merge slice candidates -> global top-3; 27-way attention. One wave per n.
__global__ __launch_bounds__(256) void attn_kernel(const float* __restrict__ x,
                                                   const float* __restrict__ ws,
                                                   float* __restrict__ out) {
    const int wid = threadIdx.x >> 6;
    const int lane = threadIdx.x & 63;
    const int gw = blockIdx.x * 4 + wid;   // 0..16383
    const int b = gw >> 12;
    const int n = gw & 4095;

    float v0 = -INFINITY, v1 = -INFINITY, v2 = -INFINITY;
    int i0 = BIGI, i1 = BIGI, i2 = BIGI;
    const int* wi = (const int*)ws;
    #pragma unroll
    for (int s = 0; s < NSLICE; ++s) {
        const size_t o = ((size_t)(b * NSLICE + s) * NN + n) * 3;
        #pragma unroll
        for (int j = 0; j < 3; ++j)
            insert_cmp(ws[CANDV_OFF + o + j], wi[CANDI_OFF + o + j], v0, i0, v1, i1, v2, i2);
    }
    const int idx3[3] = {i0, i1, i2};

    // per-lane feature meta for d = a*64 + lane  (torch reshape: K[...,a,c'] = xu[a*64+c'])
    int cc[9], dhh[9], dww[9];
    float inr[9];
    #pragma unroll
    for (int a = 0; a < 9; ++a) {
        const int d = a * 64 + lane;
        const int c = d / 9;
        const int p = d - c * 9;
        cc[a] = c; dhh[a] = p / 3 - 1; dww[a] = p - (p / 3) * 3 - 1;
        inr[a] = ws[INVN_OFF + b * ND + d];
    }
    const float q = x[((size_t)(b * 64 + lane) << 12) + n];

    float rv[27], sc[27];
    #pragma unroll
    for (int k = 0; k < 3; ++k) {
        const int m = idx3[k];
        const int hm = m >> 6, wm = m & 63;
        #pragma unroll
        for (int a = 0; a < 9; ++a) {
            const int r = hm + dhh[a], s2 = wm + dww[a];
            float val = 0.f;
            if ((unsigned)r < 64u && (unsigned)s2 < 64u)
                val = x[((size_t)(b * 64 + cc[a]) << 12) + (r << 6) + s2];
            const float rr = val * inr[a];
            rv[k * 9 + a] = rr;
            float t = q * rr;
            #pragma unroll
            for (int o2 = 32; o2 > 0; o2 >>= 1) t += __shfl_xor(t, o2);
            sc[k * 9 + a] = t * 0.125f;   // / sqrt(64)
        }
    }
    float mx = -INFINITY;
    #pragma unroll
    for (int u = 0; u < 27; ++u) mx = fmaxf(mx, sc[u]);
    float sum = 0.f;
    #pragma unroll
    for (int u = 0; u < 27; ++u) { const float e = expf(sc[u] - mx); sc[u] = e; sum += e; }
    const float inv = 1.0f / sum;
    float o = 0.f;
    #pragma unroll
    for (int u = 0; u < 27; ++u) o += sc[u] * rv[u];
    out[((size_t)gw << 6) + lane] = o * inv;
}

extern "C" void kernel_launch(void* const* d_in, const int* in_sizes, int n_in,
                              void* d_out, int out_size, void* d_ws, size_t ws_size,
                              hipStream_t stream) {
    (void)in_sizes; (void)n_in; (void)out_size; (void)ws_size;
    const float* x = (const float*)d_in[0];
    float* ws = (float*)d_ws;
    float* out = (float*)d_out;

    hipLaunchKernelGGL(norm_kernel, dim3(NB * 64), dim3(64), 0, stream, x, ws);
    hipLaunchKernelGGL(mat_kernel, dim3(2304), dim3(256), 0, stream, x, ws);
    hipLaunchKernelGGL(gram_kernel, dim3(1024), dim3(256), 0, stream, ws);
    hipLaunchKernelGGL(attn_kernel, dim3(4096), dim3(256), 0, stream, x, ws, out);
}

// Round 6
// 642.712 us; speedup vs baseline: 1.1032x; 1.1032x over previous
//
#include <hip/hip_runtime.h>
#include <cstdint>

typedef short short8 __attribute__((ext_vector_type(8)));
typedef float f32x16 __attribute__((ext_vector_type(16)));

// Problem constants
#define NB 4
#define NN 4096
#define ND 576
#define BIGI 0x7FFFFFFF
#define NSLICE 4

// ws layout: A_hi (bf16) [b][tile128][kc18][512 chunks of 16B] = 9437184 shorts,
// then A_lo same size; then (float units):
#define INVN_OFF 9437184
#define CANDV_OFF 9439488
#define CANDI_OFF 9636096
// total = 9832704 floats = 39.33 MB
// Chunk swizzle (baked into layout): chunk g = r*4 + c', source chunk
// c = c' ^ ((r>>1)&3), i.e. source k-span = c*8..c*8+7 of row r.

#define MFMA __builtin_amdgcn_mfma_f32_32x32x16_bf16

__device__ __forceinline__ unsigned short f2bf(float f) {
    unsigned u = __float_as_uint(f);
    u += 0x7FFFu + ((u >> 16) & 1u);   // round-to-nearest-even
    return (unsigned short)(u >> 16);
}

__device__ __forceinline__ void gload_lds16(const void* g, void* l) {
    __builtin_amdgcn_global_load_lds(
        (const __attribute__((address_space(1))) void*)g,
        (__attribute__((address_space(3))) void*)l, 16, 0, 0);
}

// Exact jax top_k comparator: bigger value wins; tie -> smaller index wins.
__device__ __forceinline__ void insert_cmp(float v, int m,
    float& v0, int& i0, float& v1, int& i1, float& v2, int& i2) {
    bool beat2 = (v > v2) || (v == v2 && m < i2);
    if (beat2) {
        bool beat1 = (v > v1) || (v == v1 && m < i1);
        if (beat1) {
            v2 = v1; i2 = i1;
            bool beat0 = (v > v0) || (v == v0 && m < i0);
            if (beat0) { v1 = v0; i1 = i0; v0 = v; i0 = m; }
            else       { v1 = v;  i1 = m; }
        } else { v2 = v; i2 = m; }
    }
}

// Kernel 1: per-(b,c) windowed sums of x^2 -> inv norms for the 9 kernel offsets.
__global__ __launch_bounds__(64) void norm_kernel(const float* __restrict__ x,
                                                  float* __restrict__ ws) {
    const int bc = blockIdx.x;          // b*64 + c
    const int lane = threadIdx.x;       // = column w
    const float* xp = x + ((size_t)bc << 12);
    float colsum = 0.f, v0 = 0.f, v63 = 0.f;
    for (int h = 0; h < 64; ++h) {
        const float val = xp[(h << 6) + lane];
        const float sq = val * val;
        colsum += sq;
        if (h == 0)  v0 = sq;
        if (h == 63) v63 = sq;
    }
    float total = colsum, row0 = v0, row63 = v63;
    #pragma unroll
    for (int o = 32; o > 0; o >>= 1) {
        total += __shfl_xor(total, o);
        row0  += __shfl_xor(row0, o);
        row63 += __shfl_xor(row63, o);
    }
    const float col0  = __shfl(colsum, 0);
    const float col63 = __shfl(colsum, 63);
    const float c00 = __shfl(v0, 0),  c0e = __shfl(v0, 63);
    const float ce0 = __shfl(v63, 0), cee = __shfl(v63, 63);
    if (lane < 9) {
        const int dh = lane / 3 - 1, dw = lane % 3 - 1;
        float S = total;
        if (dh == 1)  S -= row0;
        if (dh == -1) S -= row63;
        if (dw == 1)  S -= col0;
        if (dw == -1) S -= col63;
        if (dh == 1  && dw == 1)  S += c00;
        if (dh == 1  && dw == -1) S += c0e;
        if (dh == -1 && dw == 1)  S += ce0;
        if (dh == -1 && dw == -1) S += cee;
        float nrm = fmaxf(sqrtf(S), 1e-12f);
        ws[INVN_OFF + bc * 9 + lane] = 1.0f / nrm;
    }
}

// Kernel 2: split-bf16 materialization with baked chunk swizzle.
// blockIdx = (b*32+nt)*18+kc. Region = 512 chunks of 16B (8 bf16).
__global__ __launch_bounds__(256) void mat_kernel(const float* __restrict__ x,
                                                  float* __restrict__ ws) {
    const int bi = blockIdx.x;             // 2304 blocks
    const int b = bi / 576;
    const int rem = bi - b * 576;
    const int nt = rem / 18;
    const int kc = rem - nt * 18;
    unsigned short* AH = (unsigned short*)ws;
    unsigned short* AL = AH + 9437184;
    const float* invn = ws + INVN_OFF + b * 576;
    const int tid = threadIdx.x;
    #pragma unroll
    for (int hf2 = 0; hf2 < 2; ++hf2) {
        const int g = tid + hf2 * 256;     // output chunk 0..511
        const int row = g >> 2, cp = g & 3;
        const int c = cp ^ ((row >> 1) & 3);    // source chunk (swizzle)
        const int k0 = c * 8;
        const int n = nt * 128 + row;
        const int h = n >> 6, wc = n & 63;
        union { unsigned short us[8]; float4 f4; } uh, ul;
        #pragma unroll
        for (int j = 0; j < 8; ++j) {
            const int d = kc * 32 + k0 + j;
            const int ch = d / 9;
            const int p = d - ch * 9;
            const int r = h + p / 3 - 1, s2 = wc + p % 3 - 1;
            float val = 0.f;
            if ((unsigned)r < 64u && (unsigned)s2 < 64u)
                val = x[((size_t)(b * 64 + ch) << 12) + (r << 6) + s2];
            val *= invn[d];
            const unsigned short hb = f2bf(val);
            const float hfv = __uint_as_float(((unsigned)hb) << 16);
            const unsigned short lb = f2bf(val - hfv);
            uh.us[j] = hb; ul.us[j] = lb;
        }
        ((float4*)AH)[(size_t)bi * 512 + g] = uh.f4;
        ((float4*)AL)[(size_t)bi * 512 + g] = ul.f4;
    }
}

__device__ __forceinline__ short8 ldfrag(const short* p) {
    union { short8 s8; float4 f4; } u;
    u.f4 = *(const float4*)p;
    return u.s8;
}

// Kernel 3: R = A^T A via split-bf16 MFMA (hh + hl + lh), fused top-3.
// Round-6 change vs the 529-us Round-1 kernel: MFMA DEPENDENCY INTERLEAVE.
// Previously the 3 limb products were issued back-to-back into the SAME
// accumulator (same-acc reuse distance 1 -> every MFMA waits the full
// C->D latency of its predecessor; measured ~400 cy/MFMA across R0-R5).
// Now: load all 12 fragments of an h-half, then issue 3 limb PASSES each
// sweeping all 8 accumulators -> same-acc distance 8 (~256 cy of issue).
// Per-acc limb order stays hh,hl,lh -> bitwise-identical accumulation.
// Grid 256 = b(4) x nt16(16) x slice(4), 1 block/CU.  Block: 512 thr = 8 waves
// arranged 2(n) x 4(m): tile 256n x 256m per mt, mt = 0..3 (slice = 1024 m).
// Wave tile 128n x 64m. LDS 128KB = 2 x 64KB k-step buffers:
//   per buffer (shorts): AnH[0:8191] AnL[8192:16383] AmH[16384:24575] AmL[24576:32767]
// C/D: m_part = (reg&3)+8*(reg>>2)+4*(lane>>5), n_part = lane&31  [HW-verified]
__global__ void __launch_bounds__(512, 2) gram_kernel(float* ws) {
    __shared__ short sm[65536];   // 128 KB
    const int bx0 = blockIdx.x;
    const int bx = ((bx0 & 7) << 5) | (bx0 >> 3);   // XCD-chunked swizzle (256 = 8*32, bijective)
    const int b  = bx >> 6;
    const int nt = (bx >> 2) & 15;
    const int s  = bx & 3;
    const int tid = threadIdx.x;
    const int w = tid >> 6, lane = tid & 63;
    const int l31 = lane & 31, kh2 = lane >> 5;
    const int wn = w >> 2, wm = w & 3;

    const unsigned short* AH = (const unsigned short*)ws;
    const unsigned short* AL = AH + 9437184;

    // staging role: waves 0,1 -> AnH sub-regions 0,1; 2,3 -> AnL; 4,5 -> AmH; 6,7 -> AmL
    const unsigned short* srcBase = ((w >> 1) & 1) ? AL : AH;
    const bool nSide = (w < 4);
    const int cN = (b * 32 + nt * 2 + (w & 1)) * 18;          // + kc
    const int cM = (b * 32 + s * 8 + (w & 1)) * 18;           // + mt*36 + kc
    const int ldsW = (w << 12) + (lane << 3);                 // shorts

    // per-lane frag LDS offsets (shorts), swizzled chunk addressing:
    // frag(row, c) at region*4096 + (row&127)*32 + (c ^ (((row&127)>>1)&3))*8, c = kh2 + 2h
    int aoff[2][2];   // [mi][h]  (AmH base folded in; AmL = +8192)
    int boff[4][2];   // [ni][h]  (AnH base = 0;      AnL = +8192)
    #pragma unroll
    for (int mi = 0; mi < 2; ++mi)
        #pragma unroll
        for (int h = 0; h < 2; ++h) {
            const int row = wm * 64 + mi * 32 + l31;      // 0..255
            const int rl = row & 127, rt = row >> 7;
            const int c = kh2 + 2 * h;
            aoff[mi][h] = 16384 + rt * 4096 + rl * 32 + ((c ^ ((rl >> 1) & 3)) << 3);
        }
    #pragma unroll
    for (int ni = 0; ni < 4; ++ni)
        #pragma unroll
        for (int h = 0; h < 2; ++h) {
            const int row = wn * 128 + ni * 32 + l31;     // 0..255
            const int rl = row & 127, rt = row >> 7;
            const int c = kh2 + 2 * h;
            boff[ni][h] = rt * 4096 + rl * 32 + ((c ^ ((rl >> 1) & 3)) << 3);
        }

    float t0v[4], t1v[4], t2v[4];
    int   t0i[4], t1i[4], t2i[4];
    #pragma unroll
    for (int i = 0; i < 4; ++i) {
        t0v[i] = t1v[i] = t2v[i] = -INFINITY;
        t0i[i] = t1i[i] = t2i[i] = BIGI;
    }

    // prologue: stage (mt=0, kc=0) into buffer 0
    {
        const int idx = nSide ? cN : cM;
        const unsigned short* g = srcBase + ((size_t)idx << 12) + (lane << 3);
        short* d = sm + ldsW;
        #pragma unroll
        for (int i = 0; i < 8; ++i)
            gload_lds16(g + i * 512, d + i * 512);
    }
    __syncthreads();

    for (int mt = 0; mt < 4; ++mt) {
        f32x16 acc[2][4];
        #pragma unroll
        for (int mi = 0; mi < 2; ++mi)
            #pragma unroll
            for (int ni = 0; ni < 4; ++ni)
                #pragma unroll
                for (int e = 0; e < 16; ++e) acc[mi][ni][e] = 0.f;

        for (int kc = 0; kc < 18; ++kc) {
            const int cur = kc & 1;                    // mt*18 is even -> parity = kc&1
            // issue staging for the NEXT k-step first (overlaps with compute below)
            if ((mt < 3) | (kc < 17)) {
                int kc1 = kc + 1, mt1 = mt;
                if (kc1 == 18) { kc1 = 0; ++mt1; }
                const int idx = nSide ? (cN + kc1) : (cM + mt1 * 36 + kc1);
                const unsigned short* g = srcBase + ((size_t)idx << 12) + (lane << 3);
                short* d = sm + ((cur ^ 1) << 15) + ldsW;
                #pragma unroll
                for (int i = 0; i < 8; ++i)
                    gload_lds16(g + i * 512, d + i * 512);
            }
            // compute current buffer
            const short* sb = sm + (cur << 15);
            #pragma unroll
            for (int h = 0; h < 2; ++h) {
                // load ALL fragments of this h-half first
                short8 amh[2], aml[2], bh[4], bl[4];
                #pragma unroll
                for (int mi = 0; mi < 2; ++mi) {
                    amh[mi] = ldfrag(sb + aoff[mi][h]);
                    aml[mi] = ldfrag(sb + aoff[mi][h] + 8192);
                }
                #pragma unroll
                for (int ni = 0; ni < 4; ++ni) {
                    bh[ni] = ldfrag(sb + boff[ni][h]);
                    bl[ni] = ldfrag(sb + boff[ni][h] + 8192);
                }
                // limb pass 1 (hh): sweep all 8 accumulators
                #pragma unroll
                for (int ni = 0; ni < 4; ++ni)
                    #pragma unroll
                    for (int mi = 0; mi < 2; ++mi)
                        acc[mi][ni] = MFMA(amh[mi], bh[ni], acc[mi][ni], 0, 0, 0);
                // limb pass 2 (hl)
                #pragma unroll
                for (int ni = 0; ni < 4; ++ni)
                    #pragma unroll
                    for (int mi = 0; mi < 2; ++mi)
                        acc[mi][ni] = MFMA(amh[mi], bl[ni], acc[mi][ni], 0, 0, 0);
                // limb pass 3 (lh)
                #pragma unroll
                for (int ni = 0; ni < 4; ++ni)
                    #pragma unroll
                    for (int mi = 0; mi < 2; ++mi)
                        acc[mi][ni] = MFMA(aml[mi], bh[ni], acc[mi][ni], 0, 0, 0);
            }
            // single barrier per k-step: drains lgkm (frag reads done -> next step may
            // overwrite buf cur^1's predecessor) and vmcnt (next buffer staged).
            __syncthreads();
        }
        // fold acc into per-lane top-3 (per ni; n = wn*128 + ni*32 + l31)
        const int mbase = (s * 4 + mt) * 256 + wm * 64 + (kh2 << 2);
        #pragma unroll
        for (int ni = 0; ni < 4; ++ni)
            #pragma unroll
            for (int mi = 0; mi < 2; ++mi)
                #pragma unroll
                for (int v = 0; v < 16; ++v) {
                    const int m = mbase + mi * 32 + (v & 3) + 8 * (v >> 2);
                    insert_cmp(acc[mi][ni][v], m,
                               t0v[ni], t0i[ni], t1v[ni], t1i[ni], t2v[ni], t2i[ni]);
                }
    }

    // merge the two kh2 halves (same n, disjoint m) via shfl
    #pragma unroll
    for (int ni = 0; ni < 4; ++ni) {
        const float pv0 = __shfl_xor(t0v[ni], 32);
        const float pv1 = __shfl_xor(t1v[ni], 32);
        const float pv2 = __shfl_xor(t2v[ni], 32);
        const int pi0 = __shfl_xor(t0i[ni], 32);
        const int pi1 = __shfl_xor(t1i[ni], 32);
        const int pi2 = __shfl_xor(t2i[ni], 32);
        insert_cmp(pv0, pi0, t0v[ni], t0i[ni], t1v[ni], t1i[ni], t2v[ni], t2i[ni]);
        insert_cmp(pv1, pi1, t0v[ni], t0i[ni], t1v[ni], t1i[ni], t2v[ni], t2i[ni]);
        insert_cmp(pv2, pi2, t0v[ni], t0i[ni], t1v[ni], t1i[ni], t2v[ni], t2i[ni]);
    }
    // cross-wave merge through LDS: waves sharing wn cover the same 128 n rows
    // with disjoint m (wm). cv/ci live in buf0's AnH region (dead by now).
    __syncthreads();
    float* cv = (float*)sm;              // [w8][ni4][l32][3] floats (12 KB)
    int*   ci = (int*)sm + 3072;         // same shape (12 KB)
    if (kh2 == 0) {
        #pragma unroll
        for (int ni = 0; ni < 4; ++ni) {
            const int base = ((w * 4 + ni) * 32 + l31) * 3;
            cv[base] = t0v[ni]; cv[base + 1] = t1v[ni]; cv[base + 2] = t2v[ni];
            ci[base] = t0i[ni]; ci[base + 1] = t1i[ni]; ci[base + 2] = t2i[ni];
        }
    }
    __syncthreads();
    if (tid < 256) {
        const int wn2 = tid >> 7, ni = (tid >> 5) & 3, l = tid & 31;
        float v0 = -INFINITY, v1 = -INFINITY, v2 = -INFINITY;
        int i0 = BIGI, i1 = BIGI, i2 = BIGI;
        #pragma unroll
        for (int wm2 = 0; wm2 < 4; ++wm2) {
            const int w2 = wn2 * 4 + wm2;
            const int base = ((w2 * 4 + ni) * 32 + l) * 3;
            #pragma unroll
            for (int j = 0; j < 3; ++j)
                insert_cmp(cv[base + j], ci[base + j], v0, i0, v1, i1, v2, i2);
        }
        const int n_global = nt * 256 + wn2 * 128 + ni * 32 + l;
        const size_t o = ((size_t)(b * NSLICE + s) * NN + n_global) * 3;
        ws[CANDV_OFF + o] = v0; ws[CANDV_OFF + o + 1] = v1; ws[CANDV_OFF + o + 2] = v2;
        int* wi = (int*)ws;
        wi[CANDI_OFF + o] = i0; wi[CANDI_OFF + o + 1] = i1; wi[CANDI_OFF + o + 2] = i2;
    }
}

// Kernel 4: merge slice candidates -> global top-3; 27-way attention. One wave per n.
__global__ __launch_bounds__(256) void attn_kernel(const float* __restrict__ x,
                                                   const float* __restrict__ ws,
                                                   float* __restrict__ out) {
    const int wid = threadIdx.x >> 6;
    const int lane = threadIdx.x & 63;
    const int gw = blockIdx.x * 4 + wid;   // 0..16383
    const int b = gw >> 12;
    const int n = gw & 4095;

    float v0 = -INFINITY, v1 = -INFINITY, v2 = -INFINITY;
    int i0 = BIGI, i1 = BIGI, i2 = BIGI;
    const int* wi = (const int*)ws;
    #pragma unroll
    for (int s = 0; s < NSLICE; ++s) {
        const size_t o = ((size_t)(b * NSLICE + s) * NN + n) * 3;
        #pragma unroll
        for (int j = 0; j < 3; ++j)
            insert_cmp(ws[CANDV_OFF + o + j], wi[CANDI_OFF + o + j], v0, i0, v1, i1, v2, i2);
    }
    const int idx3[3] = {i0, i1, i2};

    // per-lane feature meta for d = a*64 + lane  (torch reshape: K[...,a,c'] = xu[a*64+c'])
    int cc[9], dhh[9], dww[9];
    float inr[9];
    #pragma unroll
    for (int a = 0; a < 9; ++a) {
        const int d = a * 64 + lane;
        const int c = d / 9;
        const int p = d - c * 9;
        cc[a] = c; dhh[a] = p / 3 - 1; dww[a] = p - (p / 3) * 3 - 1;
        inr[a] = ws[INVN_OFF + b * ND + d];
    }
    const float q = x[((size_t)(b * 64 + lane) << 12) + n];

    float rv[27], sc[27];
    #pragma unroll
    for (int k = 0; k < 3; ++k) {
        const int m = idx3[k];
        const int hm = m >> 6, wm = m & 63;
        #pragma unroll
        for (int a = 0; a < 9; ++a) {
            const int r = hm + dhh[a], s2 = wm + dww[a];
            float val = 0.f;
            if ((unsigned)r < 64u && (unsigned)s2 < 64u)
                val = x[((size_t)(b * 64 + cc[a]) << 12) + (r << 6) + s2];
            const float rr = val * inr[a];
            rv[k * 9 + a] = rr;
            float t = q * rr;
            #pragma unroll
            for (int o2 = 32; o2 > 0; o2 >>= 1) t += __shfl_xor(t, o2);
            sc[k * 9 + a] = t * 0.125f;   // / sqrt(64)
        }
    }
    float mx = -INFINITY;
    #pragma unroll
    for (int u = 0; u < 27; ++u) mx = fmaxf(mx, sc[u]);
    float sum = 0.f;
    #pragma unroll
    for (int u = 0; u < 27; ++u) { const float e = expf(sc[u] - mx); sc[u] = e; sum += e; }
    const float inv = 1.0f / sum;
    float o = 0.f;
    #pragma unroll
    for (int u = 0; u < 27; ++u) o += sc[u] * rv[u];
    out[((size_t)gw << 6) + lane] = o * inv;
}

extern "C" void kernel_launch(void* const* d_in, const int* in_sizes, int n_in,
                              void* d_out, int out_size, void* d_ws, size_t ws_size,
                              hipStream_t stream) {
    (void)in_sizes; (void)n_in; (void)out_size; (void)ws_size;
    const float* x = (const float*)d_in[0];
    float* ws = (float*)d_ws;
    float* out = (float*)d_out;

    hipLaunchKernelGGL(norm_kernel, dim3(NB * 64), dim3(64), 0, stream, x, ws);
    hipLaunchKernelGGL(mat_kernel, dim3(2304), dim3(256), 0, stream, x, ws);
    hipLaunchKernelGGL(gram_kernel, dim3(256), dim3(512), 0, stream, ws);
    hipLaunchKernelGGL(attn_kernel, dim3(4096), dim3(256), 0, stream, x, ws, out);
}

// Round 7
// 618.709 us; speedup vs baseline: 1.1460x; 1.0388x over previous
//
#include <hip/hip_runtime.h>
#include <cstdint>

typedef short short8 __attribute__((ext_vector_type(8)));
typedef float f32x16 __attribute__((ext_vector_type(16)));

// Problem constants
#define NB 4
#define NN 4096
#define ND 576
#define BIGI 0x7FFFFFFF
#define NSLICE 4

// ws layout: A_hi (bf16) [b][tile128][kc18][512 chunks of 16B] = 9437184 shorts,
// then A_lo same size; then (float units):
#define INVN_OFF 9437184
#define CANDV_OFF 9439488
#define CANDI_OFF 9636096
// total = 9832704 floats = 39.33 MB
// Chunk swizzle (baked into layout): chunk g = r*4 + c', source chunk
// c = c' ^ ((r>>1)&3), i.e. source k-span = c*8..c*8+7 of row r.

#define MFMA __builtin_amdgcn_mfma_f32_32x32x16_bf16

__device__ __forceinline__ unsigned short f2bf(float f) {
    unsigned u = __float_as_uint(f);
    u += 0x7FFFu + ((u >> 16) & 1u);   // round-to-nearest-even
    return (unsigned short)(u >> 16);
}

__device__ __forceinline__ void gload_lds16(const void* g, void* l) {
    __builtin_amdgcn_global_load_lds(
        (const __attribute__((address_space(1))) void*)g,
        (__attribute__((address_space(3))) void*)l, 16, 0, 0);
}

// Exact jax top_k comparator: bigger value wins; tie -> smaller index wins.
__device__ __forceinline__ void insert_cmp(float v, int m,
    float& v0, int& i0, float& v1, int& i1, float& v2, int& i2) {
    bool beat2 = (v > v2) || (v == v2 && m < i2);
    if (beat2) {
        bool beat1 = (v > v1) || (v == v1 && m < i1);
        if (beat1) {
            v2 = v1; i2 = i1;
            bool beat0 = (v > v0) || (v == v0 && m < i0);
            if (beat0) { v1 = v0; i1 = i0; v0 = v; i0 = m; }
            else       { v1 = v;  i1 = m; }
        } else { v2 = v; i2 = m; }
    }
}

// Kernel 1: per-(b,c) windowed sums of x^2 -> inv norms for the 9 kernel offsets.
__global__ __launch_bounds__(64) void norm_kernel(const float* __restrict__ x,
                                                  float* __restrict__ ws) {
    const int bc = blockIdx.x;          // b*64 + c
    const int lane = threadIdx.x;       // = column w
    const float* xp = x + ((size_t)bc << 12);
    float colsum = 0.f, v0 = 0.f, v63 = 0.f;
    for (int h = 0; h < 64; ++h) {
        const float val = xp[(h << 6) + lane];
        const float sq = val * val;
        colsum += sq;
        if (h == 0)  v0 = sq;
        if (h == 63) v63 = sq;
    }
    float total = colsum, row0 = v0, row63 = v63;
    #pragma unroll
    for (int o = 32; o > 0; o >>= 1) {
        total += __shfl_xor(total, o);
        row0  += __shfl_xor(row0, o);
        row63 += __shfl_xor(row63, o);
    }
    const float col0  = __shfl(colsum, 0);
    const float col63 = __shfl(colsum, 63);
    const float c00 = __shfl(v0, 0),  c0e = __shfl(v0, 63);
    const float ce0 = __shfl(v63, 0), cee = __shfl(v63, 63);
    if (lane < 9) {
        const int dh = lane / 3 - 1, dw = lane % 3 - 1;
        float S = total;
        if (dh == 1)  S -= row0;
        if (dh == -1) S -= row63;
        if (dw == 1)  S -= col0;
        if (dw == -1) S -= col63;
        if (dh == 1  && dw == 1)  S += c00;
        if (dh == 1  && dw == -1) S += c0e;
        if (dh == -1 && dw == 1)  S += ce0;
        if (dh == -1 && dw == -1) S += cee;
        float nrm = fmaxf(sqrtf(S), 1e-12f);
        ws[INVN_OFF + bc * 9 + lane] = 1.0f / nrm;
    }
}

// Kernel 2: split-bf16 materialization with baked chunk swizzle.
// blockIdx = (b*32+nt)*18+kc. Region = 512 chunks of 16B (8 bf16).
__global__ __launch_bounds__(256) void mat_kernel(const float* __restrict__ x,
                                                  float* __restrict__ ws) {
    const int bi = blockIdx.x;             // 2304 blocks
    const int b = bi / 576;
    const int rem = bi - b * 576;
    const int nt = rem / 18;
    const int kc = rem - nt * 18;
    unsigned short* AH = (unsigned short*)ws;
    unsigned short* AL = AH + 9437184;
    const float* invn = ws + INVN_OFF + b * 576;
    const int tid = threadIdx.x;
    #pragma unroll
    for (int hf2 = 0; hf2 < 2; ++hf2) {
        const int g = tid + hf2 * 256;     // output chunk 0..511
        const int row = g >> 2, cp = g & 3;
        const int c = cp ^ ((row >> 1) & 3);    // source chunk (swizzle)
        const int k0 = c * 8;
        const int n = nt * 128 + row;
        const int h = n >> 6, wc = n & 63;
        union { unsigned short us[8]; float4 f4; } uh, ul;
        #pragma unroll
        for (int j = 0; j < 8; ++j) {
            const int d = kc * 32 + k0 + j;
            const int ch = d / 9;
            const int p = d - ch * 9;
            const int r = h + p / 3 - 1, s2 = wc + p % 3 - 1;
            float val = 0.f;
            if ((unsigned)r < 64u && (unsigned)s2 < 64u)
                val = x[((size_t)(b * 64 + ch) << 12) + (r << 6) + s2];
            val *= invn[d];
            const unsigned short hb = f2bf(val);
            const float hfv = __uint_as_float(((unsigned)hb) << 16);
            const unsigned short lb = f2bf(val - hfv);
            uh.us[j] = hb; ul.us[j] = lb;
        }
        ((float4*)AH)[(size_t)bi * 512 + g] = uh.f4;
        ((float4*)AL)[(size_t)bi * 512 + g] = ul.f4;
    }
}

__device__ __forceinline__ short8 ldfrag(const short* p) {
    union { short8 s8; float4 f4; } u;
    u.f4 = *(const float4*)p;
    return u.s8;
}

// Kernel 3: R = A^T A via split-bf16 MFMA (hh + hl + lh), fused top-3.
// OCCUPANCY GATE (R7): V and A each round UP to 64-reg multiples (m69 steps);
// waves/SIMD = floor(512 / (Valloc + Aalloc)).  Every prior round allocated
// 192-256 -> 2 waves/SIMD (8/CU) -- the invariant behind MfmaUtil ~18%.
// Only reachable improvement: V<=64 AND A<=64 -> 128/wave -> 4 waves/SIMD
// (16 waves/CU).  Enforced via __launch_bounds__(256,4); V squeezed by
// JIT operand loads (Am per-h: 16V; B per-ni: 8V) and readfirstlane'd
// (SGPR) Am region bases.
// Grid 1024 = b(4) x nt(64: 64-row n-panels) x s(4) -> 4 blocks/CU.
// Block: 256 thr = 4 waves along m; per mt covers 64n x 256m, mt=0..3 over
// the 1024-m slice.  An (shared): LDS, 2 x 8KB double buffer, issue-early,
// one __syncthreads per kc.  Am (wave-private): direct global->VGPR.
// C/D: m_part = (reg&3)+8*(reg>>2)+4*(lane>>5), n_part = lane&31  [HW-verified]
__global__ void __launch_bounds__(256, 4) gram_kernel(float* ws) {
    __shared__ short sm[8192];   // 16 KB: buf0 {AnH[2048] AnL[2048]}, buf1 same
    const int bx0 = blockIdx.x;
    const int bx = ((bx0 & 7) << 7) | (bx0 >> 3);   // XCD swizzle (1024 = 8*128, bijective)
    const int b  = bx >> 8;
    const int nt = (bx >> 2) & 63;     // 64-row n-panel
    const int s  = bx & 3;
    const int tid = threadIdx.x;
    const int w = tid >> 6, lane = tid & 63;
    const int l31 = lane & 31, kh2 = lane >> 5;

    const unsigned short* AH = (const unsigned short*)ws;
    const unsigned short* AL = AH + 9437184;

    const int nReg = (b * 32 + (nt >> 1)) * 18;     // 128-row region; + kc
    const int nHalf = (nt & 1) * 2048;              // 64-row half (shorts)

    // An frag LDS offsets within one buffer (shorts): H at 0, L at +2048.
    // frag(row r, src chunk c) at r*32 + ((c ^ ((r>>1)&3))<<3), c = kh2 + 2h
    int boff[2][2];
    #pragma unroll
    for (int ni = 0; ni < 2; ++ni)
        #pragma unroll
        for (int h = 0; h < 2; ++h) {
            const int r = ni * 32 + l31;            // 0..63
            const int c = kh2 + 2 * h;
            boff[ni][h] = r * 32 + ((c ^ ((r >> 1) & 3)) << 3);
        }

    float t0v[2], t1v[2], t2v[2];
    int   t0i[2], t1i[2], t2i[2];
    #pragma unroll
    for (int i = 0; i < 2; ++i) {
        t0v[i] = t1v[i] = t2v[i] = -INFINITY;
        t0i[i] = t1i[i] = t2i[i] = BIGI;
    }

    // prologue: stage An[kc=0] into buffer 0 (8 KB: 2 instr/thread)
    {
        const unsigned short* gH = AH + (size_t)nReg * 4096 + nHalf + tid * 8;
        const unsigned short* gL = AL + (size_t)nReg * 4096 + nHalf + tid * 8;
        gload_lds16(gH, sm + tid * 8);
        gload_lds16(gL, sm + 2048 + tid * 8);
    }
    __syncthreads();

    for (int mt = 0; mt < 4; ++mt) {
        // Am meta for this mt: wave w owns m-cols mt*256 + w*64 .. +63
        int rif[2], amoff[2][2];
        #pragma unroll
        for (int mi = 0; mi < 2; ++mi) {
            const int mrow = s * 1024 + mt * 256 + w * 64 + mi * 32 + l31;  // 0..4095
            // region index is wave-uniform: force into SGPR
            rif[mi] = __builtin_amdgcn_readfirstlane((b * 32 + (mrow >> 7)) * 18);
            const int rl = mrow & 127;
            #pragma unroll
            for (int h = 0; h < 2; ++h) {
                const int c = kh2 + 2 * h;
                amoff[mi][h] = rl * 32 + ((c ^ ((rl >> 1) & 3)) << 3);
            }
        }

        f32x16 acc[2][2];   // [mi][ni] -> 64 AGPRs
        #pragma unroll
        for (int mi = 0; mi < 2; ++mi)
            #pragma unroll
            for (int ni = 0; ni < 2; ++ni)
                #pragma unroll
                for (int e = 0; e < 16; ++e) acc[mi][ni][e] = 0.f;

        for (int kc = 0; kc < 18; ++kc) {
            const int cur = kc & 1;     // 18 even -> parity consistent across mt
            // issue next An stage first (overlaps with this kc's compute)
            if (!(mt == 3 && kc == 17)) {
                const int nk = (kc + 1 == 18) ? 0 : kc + 1;
                const unsigned short* gH = AH + (size_t)(nReg + nk) * 4096 + nHalf + tid * 8;
                const unsigned short* gL = AL + (size_t)(nReg + nk) * 4096 + nHalf + tid * 8;
                short* dstb = sm + ((cur ^ 1) << 12);
                gload_lds16(gH, dstb + tid * 8);
                gload_lds16(gL, dstb + 2048 + tid * 8);
            }
            const short* sb = sm + (cur << 12);
            #pragma unroll
            for (int h = 0; h < 2; ++h) {
                // Am fragments for this h only (JIT: 16 VGPR live)
                short8 amh[2], aml[2];
                #pragma unroll
                for (int mi = 0; mi < 2; ++mi) {
                    const short* rH = (const short*)(AH + ((size_t)(rif[mi] + kc) << 12));
                    const short* rL = (const short*)(AL + ((size_t)(rif[mi] + kc) << 12));
                    amh[mi] = ldfrag(rH + amoff[mi][h]);
                    aml[mi] = ldfrag(rL + amoff[mi][h]);
                }
                #pragma unroll
                for (int ni = 0; ni < 2; ++ni) {
                    // B fragments JIT (8 VGPR live)
                    const short8 bh = ldfrag(sb + boff[ni][h]);
                    const short8 bl = ldfrag(sb + boff[ni][h] + 2048);
                    #pragma unroll
                    for (int mi = 0; mi < 2; ++mi) {
                        acc[mi][ni] = MFMA(amh[mi], bh, acc[mi][ni], 0, 0, 0);
                        acc[mi][ni] = MFMA(amh[mi], bl, acc[mi][ni], 0, 0, 0);
                        acc[mi][ni] = MFMA(aml[mi], bh, acc[mi][ni], 0, 0, 0);
                    }
                }
            }
            // one barrier per kc: prior reads of buf cur drained before re-stage;
            // staged buf cur^1 complete (vmcnt drained by barrier) for kc+1.
            __syncthreads();
        }
        // fold acc into per-lane top-3 (per ni; n = ni*32 + l31)
        const int mbase = s * 1024 + mt * 256 + w * 64 + (kh2 << 2);
        #pragma unroll
        for (int ni = 0; ni < 2; ++ni)
            #pragma unroll
            for (int mi = 0; mi < 2; ++mi)
                #pragma unroll
                for (int v = 0; v < 16; ++v) {
                    const int m = mbase + mi * 32 + (v & 3) + 8 * (v >> 2);
                    insert_cmp(acc[mi][ni][v], m,
                               t0v[ni], t0i[ni], t1v[ni], t1i[ni], t2v[ni], t2i[ni]);
                }
    }

    // merge the two kh2 halves (same n, disjoint m) via shfl
    #pragma unroll
    for (int ni = 0; ni < 2; ++ni) {
        const float pv0 = __shfl_xor(t0v[ni], 32);
        const float pv1 = __shfl_xor(t1v[ni], 32);
        const float pv2 = __shfl_xor(t2v[ni], 32);
        const int pi0 = __shfl_xor(t0i[ni], 32);
        const int pi1 = __shfl_xor(t1i[ni], 32);
        const int pi2 = __shfl_xor(t2i[ni], 32);
        insert_cmp(pv0, pi0, t0v[ni], t0i[ni], t1v[ni], t1i[ni], t2v[ni], t2i[ni]);
        insert_cmp(pv1, pi1, t0v[ni], t0i[ni], t1v[ni], t1i[ni], t2v[ni], t2i[ni]);
        insert_cmp(pv2, pi2, t0v[ni], t0i[ni], t1v[ni], t1i[ni], t2v[ni], t2i[ni]);
    }
    // cross-wave merge through LDS (4 waves share the 64 n-rows, disjoint m)
    __syncthreads();
    float* cv = (float*)sm;              // [w4][ni2][l32][3] floats (3 KB)
    int*   ci = (int*)sm + 768;          // same shape (3 KB)
    if (kh2 == 0) {
        #pragma unroll
        for (int ni = 0; ni < 2; ++ni) {
            const int base = ((w * 2 + ni) * 32 + l31) * 3;
            cv[base] = t0v[ni]; cv[base + 1] = t1v[ni]; cv[base + 2] = t2v[ni];
            ci[base] = t0i[ni]; ci[base + 1] = t1i[ni]; ci[base + 2] = t2i[ni];
        }
    }
    __syncthreads();
    if (tid < 64) {
        const int ni = tid >> 5, l = tid & 31;
        float v0 = -INFINITY, v1 = -INFINITY, v2 = -INFINITY;
        int i0 = BIGI, i1 = BIGI, i2 = BIGI;
        #pragma unroll
        for (int w2 = 0; w2 < 4; ++w2) {
            const int base = ((w2 * 2 + ni) * 32 + l) * 3;
            #pragma unroll
            for (int j = 0; j < 3; ++j)
                insert_cmp(cv[base + j], ci[base + j], v0, i0, v1, i1, v2, i2);
        }
        const int n_global = nt * 64 + tid;
        const size_t o = ((size_t)(b * NSLICE + s) * NN + n_global) * 3;
        ws[CANDV_OFF + o] = v0; ws[CANDV_OFF + o + 1] = v1; ws[CANDV_OFF + o + 2] = v2;
        int* wi = (int*)ws;
        wi[CANDI_OFF + o] = i0; wi[CANDI_OFF + o + 1] = i1; wi[CANDI_OFF + o + 2] = i2;
    }
}

// Kernel 4: merge slice candidates -> global top-3; 27-way attention. One wave per n.
__global__ __launch_bounds__(256) void attn_kernel(const float* __restrict__ x,
                                                   const float* __restrict__ ws,
                                                   float* __restrict__ out) {
    const int wid = threadIdx.x >> 6;
    const int lane = threadIdx.x & 63;
    const int gw = blockIdx.x * 4 + wid;   // 0..16383
    const int b = gw >> 12;
    const int n = gw & 4095;

    float v0 = -INFINITY, v1 = -INFINITY, v2 = -INFINITY;
    int i0 = BIGI, i1 = BIGI, i2 = BIGI;
    const int* wi = (const int*)ws;
    #pragma unroll
    for (int s = 0; s < NSLICE; ++s) {
        const size_t o = ((size_t)(b * NSLICE + s) * NN + n) * 3;
        #pragma unroll
        for (int j = 0; j < 3; ++j)
            insert_cmp(ws[CANDV_OFF + o + j], wi[CANDI_OFF + o + j], v0, i0, v1, i1, v2, i2);
    }
    const int idx3[3] = {i0, i1, i2};

    // per-lane feature meta for d = a*64 + lane  (torch reshape: K[...,a,c'] = xu[a*64+c'])
    int cc[9], dhh[9], dww[9];
    float inr[9];
    #pragma unroll
    for (int a = 0; a < 9; ++a) {
        const int d = a * 64 + lane;
        const int c = d / 9;
        const int p = d - c * 9;
        cc[a] = c; dhh[a] = p / 3 - 1; dww[a] = p - (p / 3) * 3 - 1;
        inr[a] = ws[INVN_OFF + b * ND + d];
    }
    const float q = x[((size_t)(b * 64 + lane) << 12) + n];

    float rv[27], sc[27];
    #pragma unroll
    for (int k = 0; k < 3; ++k) {
        const int m = idx3[k];
        const int hm = m >> 6, wm = m & 63;
        #pragma unroll
        for (int a = 0; a < 9; ++a) {
            const int r = hm + dhh[a], s2 = wm + dww[a];
            float val = 0.f;
            if ((unsigned)r < 64u && (unsigned)s2 < 64u)
                val = x[((size_t)(b * 64 + cc[a]) << 12) + (r << 6) + s2];
            const float rr = val * inr[a];
            rv[k * 9 + a] = rr;
            float t = q * rr;
            #pragma unroll
            for (int o2 = 32; o2 > 0; o2 >>= 1) t += __shfl_xor(t, o2);
            sc[k * 9 + a] = t * 0.125f;   // / sqrt(64)
        }
    }
    float mx = -INFINITY;
    #pragma unroll
    for (int u = 0; u < 27; ++u) mx = fmaxf(mx, sc[u]);
    float sum = 0.f;
    #pragma unroll
    for (int u = 0; u < 27; ++u) { const float e = expf(sc[u] - mx); sc[u] = e; sum += e; }
    const float inv = 1.0f / sum;
    float o = 0.f;
    #pragma unroll
    for (int u = 0; u < 27; ++u) o += sc[u] * rv[u];
    out[((size_t)gw << 6) + lane] = o * inv;
}

extern "C" void kernel_launch(void* const* d_in, const int* in_sizes, int n_in,
                              void* d_out, int out_size, void* d_ws, size_t ws_size,
                              hipStream_t stream) {
    (void)in_sizes; (void)n_in; (void)out_size; (void)ws_size;
    const float* x = (const float*)d_in[0];
    float* ws = (float*)d_ws;
    float* out = (float*)d_out;

    hipLaunchKernelGGL(norm_kernel, dim3(NB * 64), dim3(64), 0, stream, x, ws);
    hipLaunchKernelGGL(mat_kernel, dim3(2304), dim3(256), 0, stream, x, ws);
    hipLaunchKernelGGL(gram_kernel, dim3(1024), dim3(256), 0, stream, ws);
    hipLaunchKernelGGL(attn_kernel, dim3(4096), dim3(256), 0, stream, x, ws, out);
}